// Round 14
// baseline (18153.258 us; speedup 1.0000x reference)
//
#include <hip/hip_runtime.h>
#include <math.h>

#define Bsz 32768
#define Hd  1024
#define Vn  9
#define Tn  20
#define EOSv 8
#define KFC 784
#define PLANE 33554432ull   // 32768*1024 elems per f16 plane

typedef float f4 __attribute__((ext_vector_type(4)));
typedef float f32x16 __attribute__((ext_vector_type(16)));
typedef _Float16 h8 __attribute__((ext_vector_type(8)));
typedef unsigned short us4 __attribute__((ext_vector_type(4)));
typedef unsigned short us8v __attribute__((ext_vector_type(8)));

__device__ __forceinline__ unsigned short f16_rne(float x) {
    _Float16 h = (_Float16)x;
    return __builtin_bit_cast(unsigned short, h);
}
__device__ __forceinline__ float f16_val(unsigned short u) {
    return (float)__builtin_bit_cast(_Float16, u);
}
__device__ __forceinline__ void split2h(float x, unsigned short& p0, unsigned short& p1) {
    p0 = f16_rne(x);
    float r = x - f16_val(p0);
    p1 = f16_rne(r);
}
__device__ __forceinline__ int slotr(int r) { return r ^ ((r >> 3) & 3); }

// ---------------- init ----------------
__global__ __launch_bounds__(256) void k_init(int* __restrict__ st,
                                              float* __restrict__ lenf) {
    int i = blockIdx.x * 256 + threadIdx.x;
    if (i < Bsz) { st[i] = 0; lenf[i] = (float)Tn; }
}

// ---------------- giTab[tk][n] = w_ih[n][tk] + b_ih[n] ----------------
__global__ __launch_bounds__(256) void k_prep(const float* __restrict__ wih,
                                              const float* __restrict__ bih,
                                              float* __restrict__ giTab) {
    int i = blockIdx.x * 256 + threadIdx.x;
    int tk = i / 3072, n = i - tk * 3072;
    giTab[i] = wih[(size_t)n * Vn + tk] + bih[n];
}

// ---------------- w_hh -> pre-tiled f16x2 planes (fragment order) ----------------
// unit u = ((ct*64 + kc16)*2 + p), 1KB: lane l holds B[k][n], n=ct*32+(l&31),
// k = kc16*16 + (l>>5)*8 + i
__global__ __launch_bounds__(256) void k_prepB(const float* __restrict__ whh,
                                               unsigned short* __restrict__ wp) {
    int g = blockIdx.x * 256 + threadIdx.x;   // 3072 blocks: 12288 units x 64 lanes
    int lane = g & 63, u = g >> 6;
    int p = u & 1, kc = (u >> 1) & 63, ct = u >> 7;
    int col = ct * 32 + (lane & 31);
    int k = kc * 16 + (lane >> 5) * 8;
    const float* src = whh + (size_t)col * Hd + k;
    unsigned short v[8];
    #pragma unroll
    for (int i = 0; i < 8; ++i) {
        unsigned short s0, s1; split2h(src[i], s0, s1);
        v[i] = (p == 0) ? s0 : s1;
    }
    unsigned short* dst = wp + (size_t)u * 512 + lane * 8;
    us4 w0; w0[0]=v[0]; w0[1]=v[1]; w0[2]=v[2]; w0[3]=v[3];
    us4 w1; w1[0]=v[4]; w1[1]=v[5]; w1[2]=v[6]; w1[3]=v[7];
    *(us4*)dst = w0;
    *(us4*)(dst + 4) = w1;
}

// ---------------- h0 = gelu(x @ fc_w^T) -> fp32 h AND f16x2 planes ----------------
__global__ __launch_bounds__(256) void k_fcP(const float* __restrict__ x,
                                             const float* __restrict__ fcw,
                                             float* __restrict__ h0,
                                             unsigned short* __restrict__ hp) {
    __shared__ float As[16][68];
    __shared__ float Ws[16][68];
    const int tid = threadIdx.x;
    const int tx = tid & 15, ty = tid >> 4;
    const int m0 = blockIdx.x * 64, n0 = blockIdx.y * 64;
    const int lrow = tid >> 2, lkc = (tid & 3) << 2;
    float acc[4][4] = {};
    for (int k0 = 0; k0 < KFC; k0 += 16) {
        f4 a = *(const f4*)(x   + (size_t)(m0 + lrow) * KFC + k0 + lkc);
        f4 w = *(const f4*)(fcw + (size_t)(n0 + lrow) * KFC + k0 + lkc);
        #pragma unroll
        for (int q = 0; q < 4; ++q) { As[lkc + q][lrow] = a[q]; Ws[lkc + q][lrow] = w[q]; }
        __syncthreads();
        #pragma unroll
        for (int kk = 0; kk < 16; ++kk) {
            f4 av = *(const f4*)&As[kk][ty * 4];
            f4 wv = *(const f4*)&Ws[kk][tx * 4];
            #pragma unroll
            for (int i = 0; i < 4; ++i)
                #pragma unroll
                for (int j = 0; j < 4; ++j)
                    acc[i][j] = fmaf(av[i], wv[j], acc[i][j]);
        }
        __syncthreads();
    }
    #pragma unroll
    for (int i = 0; i < 4; ++i) {
        int b = m0 + ty * 4 + i;
        int cb = n0 + tx * 4;
        f4 hv;
        us4 q0, q1;
        #pragma unroll
        for (int j = 0; j < 4; ++j) {
            float v = acc[i][j];
            float gl = 0.5f * v * (1.0f + erff(v * 0.70710678118654752f));
            hv[j] = gl;
            unsigned short s0, s1; split2h(gl, s0, s1);
            q0[j] = s0; q1[j] = s1;
        }
        *(f4*)&h0[(size_t)b * Hd + cb] = hv;
        *(us4*)&hp[0 * PLANE + (size_t)b * Hd + cb] = q0;
        *(us4*)&hp[1 * PLANE + (size_t)b * Hd + cb] = q1;
    }
}

// ---------------- fused GRU step: f16x2, BM=128, BK=32, B direct from global ----------------
// 256 thr = 4 waves (2m x 2n); block 128 rows x 64 h-cols x 3 gates; 32 iters
// LDS carries only A (32KB); B streams from L2-resident pre-tiled wp
__global__ __launch_bounds__(256, 2) void k_step(
        const unsigned short* __restrict__ hp, float* __restrict__ h,
        const unsigned short* __restrict__ wp, const float* __restrict__ bhh,
        const float* __restrict__ giTab, const int* __restrict__ st) {
    __shared__ unsigned short Asm[2][2 * 4 * 128 * 8];   // 2 x 16384 B
    const int tid = threadIdx.x;
    const int lane = tid & 63, wid = tid >> 6;
    const int wm = wid >> 1, wn = wid & 1;
    const int l31 = lane & 31, lh = lane >> 5;

    // cg pinned to XCD: B slice (2 cg x 786KB = 1.5MB) L2-resident all step
    const int w = blockIdx.x;
    const int cg = (w & 7) * 2 + ((w >> 3) & 1);   // 0..15
    const int rb = w >> 4;                         // 0..255
    const int m_blk = rb * 128;
    const int c0 = cg * 64;

    f32x16 acc[2][3];
    #pragma unroll
    for (int mt = 0; mt < 2; ++mt)
        #pragma unroll
        for (int g = 0; g < 3; ++g)
            #pragma unroll
            for (int e = 0; e < 16; ++e) acc[mt][g][e] = 0.0f;

    const int ar = tid >> 1;            // row 0..127
    const int kqw = (tid & 1) << 1;     // kq base 0/2 (8-elem granules)
    const int wslot = slotr(ar);
    int rslot[2];
    #pragma unroll
    for (int mt = 0; mt < 2; ++mt) rslot[mt] = slotr(wm * 64 + mt * 32 + l31);

    // B fragment base pointers (pre-tiled wp, f16x2), per gate
    const unsigned short* bg[3];
    #pragma unroll
    for (int g = 0; g < 3; ++g) {
        int ct = g * 32 + cg * 2 + wn;
        bg[g] = wp + (size_t)ct * 64 * 2 * 512 + (size_t)lane * 8;
    }

    us8v pa[2][2];   // [plane][half] A(s+1) fragments (pure copy, no VALU)
    auto load_a = [&](int s) {
        const size_t base = (size_t)(m_blk + ar) * Hd + (s << 5) + (kqw << 3);
        pa[0][0] = *(const us8v*)&hp[0 * PLANE + base];
        pa[0][1] = *(const us8v*)&hp[0 * PLANE + base + 8];
        pa[1][0] = *(const us8v*)&hp[1 * PLANE + base];
        pa[1][1] = *(const us8v*)&hp[1 * PLANE + base + 8];
    };
    auto write_a = [&](int bufi) {
        #pragma unroll
        for (int p = 0; p < 2; ++p)
            #pragma unroll
            for (int half = 0; half < 2; ++half)
                *(us8v*)&Asm[bufi][((p * 4 + kqw + half) * 128 + wslot) * 8] = pa[p][half];
    };

    load_a(0);
    write_a(0);
    load_a(1);
    __syncthreads();

    for (int s = 0; s < 32; ++s) {
        const int bi = s & 1;
        if (s < 31) write_a(bi ^ 1);   // A(s+1) regs -> LDS
        if (s < 30) load_a(s + 2);     // A(s+2) global -> regs
        // compute chunk s: two 16-k sub-chunks; B streamed from global (L2)
        #pragma unroll
        for (int kc = 0; kc < 2; ++kc) {
            h8 af[2][2];
            #pragma unroll
            for (int mt = 0; mt < 2; ++mt)
                #pragma unroll
                for (int p = 0; p < 2; ++p)
                    af[mt][p] = *(const h8*)&Asm[bi][((p * 4 + kc * 2 + lh) * 128 + rslot[mt]) * 8];
            #pragma unroll
            for (int g = 0; g < 3; ++g) {
                const unsigned short* bp = bg[g] + ((size_t)(s * 2 + kc) * 2) * 512;
                h8 b0 = *(const h8*)(bp);
                h8 b1 = *(const h8*)(bp + 512);
                #pragma unroll
                for (int mt = 0; mt < 2; ++mt) {
                    f32x16 c = acc[mt][g];
                    c = __builtin_amdgcn_mfma_f32_32x32x16_f16(af[mt][0], b1, c, 0, 0, 0);
                    c = __builtin_amdgcn_mfma_f32_32x32x16_f16(af[mt][1], b0, c, 0, 0, 0);
                    c = __builtin_amdgcn_mfma_f32_32x32x16_f16(af[mt][0], b0, c, 0, 0, 0);
                    acc[mt][g] = c;
                }
            }
        }
        __syncthreads();
    }

    // fused GRU epilogue; hold = exact fp32 h (in-place safe: same thread r/w)
    const int col = c0 + wn * 32 + l31;
    const float bhr = bhh[col], bhz = bhh[Hd + col], bhn = bhh[2 * Hd + col];
    #pragma unroll
    for (int mt = 0; mt < 2; ++mt) {
        #pragma unroll
        for (int reg = 0; reg < 16; ++reg) {
            const int row = m_blk + wm * 64 + mt * 32 + 4 * lh + (reg & 3) + 8 * (reg >> 2);
            const int tk = st[row] & 15;
            const float* gi = giTab + tk * 3072;
            float rr = 1.0f / (1.0f + expf(-(gi[col] + acc[mt][0][reg] + bhr)));
            float zz = 1.0f / (1.0f + expf(-(gi[Hd + col] + acc[mt][1][reg] + bhz)));
            float nn = tanhf(gi[2 * Hd + col] + rr * (acc[mt][2][reg] + bhn));
            const size_t off = (size_t)row * Hd + col;
            float hold = h[off];
            h[off] = (1.0f - zz) * nn + zz * hold;
        }
    }
}

// ---------------- proj: logits + gumbel argmax + one-hot + EOS + plane write ----------------
__global__ __launch_bounds__(256) void k_projP(const float* __restrict__ hnew,
        unsigned short* __restrict__ hp,
        const float* __restrict__ pw, const float* __restrict__ pb,
        const float* __restrict__ gum, const float* __restrict__ tau,
        float* __restrict__ msg, float* __restrict__ lenf,
        int* __restrict__ st, int t) {
    const int lane = threadIdx.x & 63;
    const int wv = threadIdx.x >> 6;
    const int b = blockIdx.x * 4 + wv;
    const float* hr = hnew + (size_t)b * Hd;
    float s[Vn] = {};
    float vals[16];
    #pragma unroll
    for (int c0 = 0; c0 < 16; c0 += 4) {
        f4 hv = *(const f4*)(hr + lane * 16 + c0);
        #pragma unroll
        for (int q = 0; q < 4; ++q) vals[c0 + q] = hv[q];
        #pragma unroll
        for (int v = 0; v < Vn; ++v) {
            f4 pv = *(const f4*)(pw + (size_t)v * Hd + lane * 16 + c0);
            #pragma unroll
            for (int q = 0; q < 4; ++q) s[v] = fmaf(hv[q], pv[q], s[v]);
        }
    }
    us8v o0[2], o1[2];
    #pragma unroll
    for (int hh = 0; hh < 2; ++hh)
        #pragma unroll
        for (int e = 0; e < 8; ++e) {
            unsigned short q0, q1;
            split2h(vals[hh * 8 + e], q0, q1);
            o0[hh][e] = q0; o1[hh][e] = q1;
        }
    size_t base = (size_t)b * Hd + lane * 16;
    #pragma unroll
    for (int hh = 0; hh < 2; ++hh) {
        *(us8v*)&hp[0 * PLANE + base + hh * 8] = o0[hh];
        *(us8v*)&hp[1 * PLANE + base + hh * 8] = o1[hh];
    }
    #pragma unroll
    for (int v = 0; v < Vn; ++v)
        #pragma unroll
        for (int off = 32; off > 0; off >>= 1)
            s[v] += __shfl_xor(s[v], off, 64);
    if (lane == 0) {
        const float tv = tau[0];
        float zv[Vn];
        #pragma unroll
        for (int v = 0; v < Vn; ++v)
            zv[v] = (s[v] + pb[v] + gum[(size_t)b * Vn + v]) / tv;
        int idx = 0; float m = zv[0];
        #pragma unroll
        for (int v = 1; v < Vn; ++v)
            if (zv[v] > m) { m = zv[v]; idx = v; }
        float* orow = msg + ((size_t)b * Tn + t) * Vn;
        #pragma unroll
        for (int v = 0; v < Vn; ++v) orow[v] = (v == idx) ? 1.0f : 0.0f;
        const int old = st[b];
        const int fn = old >> 4;
        st[b] = idx | (((fn != 0) || (idx == EOSv)) ? 16 : 0);
        if (idx == EOSv && fn == 0) lenf[b] = (float)(t + 1);
    }
}

extern "C" void kernel_launch(void* const* d_in, const int* in_sizes, int n_in,
                              void* d_out, int out_size, void* d_ws, size_t ws_size,
                              hipStream_t stream) {
    const float* x   = (const float*)d_in[0];
    const float* tau = (const float*)d_in[1];
    const float* fcw = (const float*)d_in[2];
    const float* wih = (const float*)d_in[3];
    const float* whh = (const float*)d_in[4];
    const float* bih = (const float*)d_in[5];
    const float* bhh = (const float*)d_in[6];
    const float* pw  = (const float*)d_in[7];
    const float* pb  = (const float*)d_in[8];
    const float* gum = (const float*)d_in[9];

    float* msg  = (float*)d_out;
    float* lenf = msg + (size_t)Bsz * Tn * Vn;

    // workspace: 281,260,032 B (round-11-proven)
    char* ws = (char*)d_ws;
    float*          h     = (float*)ws;                           // 134,217,728
    unsigned short* hp    = (unsigned short*)(ws + 134217728ull); // 134,217,728 (2 f16 planes)
    unsigned short* wpb   = (unsigned short*)(ws + 268435456ull); //  12,582,912
    float*          giTab = (float*)(ws + 281018368ull);          //     110,592
    int*            st    = (int*)  (ws + 281128960ull);          //     131,072

    k_init<<<Bsz / 256, 256, 0, stream>>>(st, lenf);
    k_prep<<<108, 256, 0, stream>>>(wih, bih, giTab);
    k_prepB<<<3072, 256, 0, stream>>>(whh, wpb);
    k_fcP<<<dim3(Bsz / 64, Hd / 64), 256, 0, stream>>>(x, fcw, h, hp);
    for (int t = 0; t < Tn; ++t) {
        k_step<<<4096, 256, 0, stream>>>(hp, h, wpb, bhh, giTab, st);
        k_projP<<<Bsz / 4, 256, 0, stream>>>(h, hp, pw, pb,
                                             gum + (size_t)t * Bsz * Vn,
                                             tau, msg, lenf, st, t);
    }
}

// Round 15
// 16655.450 us; speedup vs baseline: 1.0899x; 1.0899x over previous
//
#include <hip/hip_runtime.h>
#include <math.h>

#define Bsz 32768
#define Hd  1024
#define Vn  9
#define Tn  20
#define EOSv 8
#define KFC 784
#define PLANE 33554432ull   // 32768*1024 elems per f16 plane

typedef float f4 __attribute__((ext_vector_type(4)));
typedef float f32x16 __attribute__((ext_vector_type(16)));
typedef _Float16 h8 __attribute__((ext_vector_type(8)));
typedef unsigned short us4 __attribute__((ext_vector_type(4)));
typedef unsigned short us8v __attribute__((ext_vector_type(8)));

__device__ __forceinline__ unsigned short f16_rne(float x) {
    _Float16 h = (_Float16)x;
    return __builtin_bit_cast(unsigned short, h);
}
__device__ __forceinline__ float f16_val(unsigned short u) {
    return (float)__builtin_bit_cast(_Float16, u);
}
__device__ __forceinline__ void split2h(float x, unsigned short& p0, unsigned short& p1) {
    p0 = f16_rne(x);
    float r = x - f16_val(p0);
    p1 = f16_rne(r);
}
__device__ __forceinline__ int slotr(int r) { return r ^ ((r >> 3) & 3); }

__device__ __forceinline__ void gload16(const void* g, void* l) {
    __builtin_amdgcn_global_load_lds(
        (const __attribute__((address_space(1))) unsigned int*)g,
        (__attribute__((address_space(3))) unsigned int*)l, 16, 0, 0);
}

// counted waits WITHOUT sched_barrier pins (compiler stays free to schedule)
#define V_WAIT(N) asm volatile("s_waitcnt vmcnt(" #N ")" ::: "memory")
#define L_WAIT0   asm volatile("s_waitcnt lgkmcnt(0)" ::: "memory")
#define BARRIER   asm volatile("s_barrier" ::: "memory")

// ---------------- init ----------------
__global__ __launch_bounds__(256) void k_init(int* __restrict__ st,
                                              float* __restrict__ lenf) {
    int i = blockIdx.x * 256 + threadIdx.x;
    if (i < Bsz) { st[i] = 0; lenf[i] = (float)Tn; }
}

// ---------------- giTab[tk][n] = w_ih[n][tk] + b_ih[n] ----------------
__global__ __launch_bounds__(256) void k_prep(const float* __restrict__ wih,
                                              const float* __restrict__ bih,
                                              float* __restrict__ giTab) {
    int i = blockIdx.x * 256 + threadIdx.x;
    int tk = i / 3072, n = i - tk * 3072;
    giTab[i] = wih[(size_t)n * Vn + tk] + bih[n];
}

// ---------------- w_hh -> pre-tiled f16x2 planes (fragment order) ----------------
__global__ __launch_bounds__(256) void k_prepB(const float* __restrict__ whh,
                                               unsigned short* __restrict__ wp) {
    int g = blockIdx.x * 256 + threadIdx.x;   // 3072 blocks: 12288 units x 64 lanes
    int lane = g & 63, u = g >> 6;
    int p = u & 1, kc = (u >> 1) & 63, ct = u >> 7;
    int col = ct * 32 + (lane & 31);
    int k = kc * 16 + (lane >> 5) * 8;
    const float* src = whh + (size_t)col * Hd + k;
    unsigned short v[8];
    #pragma unroll
    for (int i = 0; i < 8; ++i) {
        unsigned short s0, s1; split2h(src[i], s0, s1);
        v[i] = (p == 0) ? s0 : s1;
    }
    unsigned short* dst = wp + (size_t)u * 512 + lane * 8;
    us4 w0; w0[0]=v[0]; w0[1]=v[1]; w0[2]=v[2]; w0[3]=v[3];
    us4 w1; w1[0]=v[4]; w1[1]=v[5]; w1[2]=v[6]; w1[3]=v[7];
    *(us4*)dst = w0;
    *(us4*)(dst + 4) = w1;
}

// ---------------- h0 = gelu(x @ fc_w^T) -> fp32 h AND f16x2 planes ----------------
__global__ __launch_bounds__(256) void k_fcP(const float* __restrict__ x,
                                             const float* __restrict__ fcw,
                                             float* __restrict__ h0,
                                             unsigned short* __restrict__ hp) {
    __shared__ float As[16][68];
    __shared__ float Ws[16][68];
    const int tid = threadIdx.x;
    const int tx = tid & 15, ty = tid >> 4;
    const int m0 = blockIdx.x * 64, n0 = blockIdx.y * 64;
    const int lrow = tid >> 2, lkc = (tid & 3) << 2;
    float acc[4][4] = {};
    for (int k0 = 0; k0 < KFC; k0 += 16) {
        f4 a = *(const f4*)(x   + (size_t)(m0 + lrow) * KFC + k0 + lkc);
        f4 w = *(const f4*)(fcw + (size_t)(n0 + lrow) * KFC + k0 + lkc);
        #pragma unroll
        for (int q = 0; q < 4; ++q) { As[lkc + q][lrow] = a[q]; Ws[lkc + q][lrow] = w[q]; }
        __syncthreads();
        #pragma unroll
        for (int kk = 0; kk < 16; ++kk) {
            f4 av = *(const f4*)&As[kk][ty * 4];
            f4 wv = *(const f4*)&Ws[kk][tx * 4];
            #pragma unroll
            for (int i = 0; i < 4; ++i)
                #pragma unroll
                for (int j = 0; j < 4; ++j)
                    acc[i][j] = fmaf(av[i], wv[j], acc[i][j]);
        }
        __syncthreads();
    }
    #pragma unroll
    for (int i = 0; i < 4; ++i) {
        int b = m0 + ty * 4 + i;
        int cb = n0 + tx * 4;
        f4 hv;
        us4 q0, q1;
        #pragma unroll
        for (int j = 0; j < 4; ++j) {
            float v = acc[i][j];
            float gl = 0.5f * v * (1.0f + erff(v * 0.70710678118654752f));
            hv[j] = gl;
            unsigned short s0, s1; split2h(gl, s0, s1);
            q0[j] = s0; q1[j] = s1;
        }
        *(f4*)&h0[(size_t)b * Hd + cb] = hv;
        *(us4*)&hp[0 * PLANE + (size_t)b * Hd + cb] = q0;
        *(us4*)&hp[1 * PLANE + (size_t)b * Hd + cb] = q1;
    }
}

// ================= shared geometry for both k_step variants =================
// 256 thr = 4 waves (2m x 2n); block 128 rows x 64 h-cols x 3 gates; BK=16 dbuf
// VARIANT 0 (A): __syncthreads() per iter (round-11 reference)
// VARIANT 1 (B): raw s_barrier + counted vmcnt, NO sched_barrier pins
template <int VARIANT>
__device__ __forceinline__ void step_body(
        const unsigned short* __restrict__ hp, float* __restrict__ h,
        const unsigned short* __restrict__ wp, const float* __restrict__ bhh,
        const float* __restrict__ giTab, const int* __restrict__ st,
        unsigned short* Asm0, unsigned short* Asm1,
        unsigned short* Bsm0, unsigned short* Bsm1) {
    const int tid = threadIdx.x;
    const int lane = tid & 63, wid = tid >> 6;
    const int wm = wid >> 1, wn = wid & 1;
    const int l31 = lane & 31, lh = lane >> 5;

    const int w = blockIdx.x;
    const int cg = (w & 7) * 2 + ((w >> 3) & 1);   // 0..15, pinned to XCD
    const int rb = w >> 4;                         // 0..255
    const int m_blk = rb * 128;
    const int c0 = cg * 64;

    f32x16 acc[2][3];
    #pragma unroll
    for (int mt = 0; mt < 2; ++mt)
        #pragma unroll
        for (int g = 0; g < 3; ++g)
            #pragma unroll
            for (int e = 0; e < 16; ++e) acc[mt][g][e] = 0.0f;

    const int ar = tid >> 1;          // row 0..127
    const int kh = tid & 1;           // 8-k granule within 16-chunk
    const int wslot = slotr(ar);
    int rslot[2];
    #pragma unroll
    for (int mt = 0; mt < 2; ++mt) rslot[mt] = slotr(wm * 64 + mt * 32 + l31);

    us8v pa[2];
    auto load_a = [&](int s) {
        const size_t base = (size_t)(m_blk + ar) * Hd + (s << 4) + (kh << 3);
        pa[0] = *(const us8v*)&hp[0 * PLANE + base];
        pa[1] = *(const us8v*)&hp[1 * PLANE + base];
    };
    auto write_a = [&](unsigned short* buf) {
        *(us8v*)&buf[((0 * 2 + kh) * 128 + wslot) * 8] = pa[0];
        *(us8v*)&buf[((1 * 2 + kh) * 128 + wslot) * 8] = pa[1];
    };
    auto stage_b = [&](int s, unsigned short* buf) {
        #pragma unroll
        for (int q = 0; q < 3; ++q) {
            const int u = wid * 3 + q;            // 0..11
            const int ctl = u >> 1, p = u & 1;
            const int g = ctl >> 1, wnl = ctl & 1;
            const int ct = g * 32 + cg * 2 + wnl;
            const unsigned short* src = wp + ((size_t)(ct * 64 + s) * 2 + p) * 512 + lane * 8;
            gload16(src, &buf[u * 512]);
        }
    };
    auto compute = [&](const unsigned short* Abuf, const unsigned short* Bbuf) {
        h8 af[2][2];
        #pragma unroll
        for (int mt = 0; mt < 2; ++mt)
            #pragma unroll
            for (int p = 0; p < 2; ++p)
                af[mt][p] = *(const h8*)&Abuf[((p * 2 + lh) * 128 + rslot[mt]) * 8];
        #pragma unroll
        for (int g = 0; g < 3; ++g) {
            const int ub = (g * 2 + wn) * 2;
            h8 b0 = *(const h8*)&Bbuf[(ub + 0) * 512 + lane * 8];
            h8 b1 = *(const h8*)&Bbuf[(ub + 1) * 512 + lane * 8];
            #pragma unroll
            for (int mt = 0; mt < 2; ++mt) {
                f32x16 c = acc[mt][g];
                c = __builtin_amdgcn_mfma_f32_32x32x16_f16(af[mt][0], b1, c, 0, 0, 0);
                c = __builtin_amdgcn_mfma_f32_32x32x16_f16(af[mt][1], b0, c, 0, 0, 0);
                c = __builtin_amdgcn_mfma_f32_32x32x16_f16(af[mt][0], b0, c, 0, 0, 0);
                acc[mt][g] = c;
            }
        }
    };

    if (VARIANT == 0) {
        stage_b(0, Bsm0);
        load_a(0);
        write_a(Asm0);
        load_a(1);
        __syncthreads();
        for (int s = 0; s < 64; ++s) {
            const int bi = s & 1;
            unsigned short* Acur = bi ? Asm1 : Asm0;
            unsigned short* Anxt = bi ? Asm0 : Asm1;
            unsigned short* Bcur = bi ? Bsm1 : Bsm0;
            unsigned short* Bnxt = bi ? Bsm0 : Bsm1;
            if (s < 63) {
                stage_b(s + 1, Bnxt);
                write_a(Anxt);
            }
            if (s < 62) load_a(s + 2);
            compute(Acur, Bcur);
            __syncthreads();
        }
    } else {
        // prologue: drain fully once, then enter steady state [A(1):6 in flight]
        stage_b(0, Bsm0);
        load_a(0);
        write_a(Asm0);        // compiler auto-waits pa deps
        load_a(1);
        L_WAIT0;
        V_WAIT(0);
        BARRIER;
        for (int s = 0; s < 64; ++s) {
            const int bi = s & 1;
            unsigned short* Acur = bi ? Asm1 : Asm0;
            unsigned short* Anxt = bi ? Asm0 : Asm1;
            unsigned short* Bcur = bi ? Bsm1 : Bsm0;
            unsigned short* Bnxt = bi ? Bsm0 : Bsm1;
            if (s < 63) {
                stage_b(s + 1, Bnxt);   // +B(s+1):3
                write_a(Anxt);          // auto vmcnt retires A(s+1)
            }
            if (s < 62) load_a(s + 2);  // +A(s+2):6
            compute(Acur, Bcur);
            if (s < 63) {
                L_WAIT0;                // my ds_writes visible
                if (s < 62) { V_WAIT(6); }   // retire B(s+1), keep A(s+2) in flight
                else        { V_WAIT(0); }   // s=62: only B(63) outstanding
                BARRIER;
            }
        }
    }

    // fused GRU epilogue; hold = exact fp32 h (in-place safe: same thread r/w)
    const int col = c0 + wn * 32 + l31;
    const float bhr = bhh[col], bhz = bhh[Hd + col], bhn = bhh[2 * Hd + col];
    #pragma unroll
    for (int mt = 0; mt < 2; ++mt) {
        #pragma unroll
        for (int reg = 0; reg < 16; ++reg) {
            const int row = m_blk + wm * 64 + mt * 32 + 4 * lh + (reg & 3) + 8 * (reg >> 2);
            const int tk = st[row] & 15;
            const float* gi = giTab + tk * 3072;
            float rr = 1.0f / (1.0f + expf(-(gi[col] + acc[mt][0][reg] + bhr)));
            float zz = 1.0f / (1.0f + expf(-(gi[Hd + col] + acc[mt][1][reg] + bhz)));
            float nn = tanhf(gi[2 * Hd + col] + rr * (acc[mt][2][reg] + bhn));
            const size_t off = (size_t)row * Hd + col;
            float hold = h[off];
            h[off] = (1.0f - zz) * nn + zz * hold;
        }
    }
}

__global__ __launch_bounds__(256, 3) void k_stepA(
        const unsigned short* __restrict__ hp, float* __restrict__ h,
        const unsigned short* __restrict__ wp, const float* __restrict__ bhh,
        const float* __restrict__ giTab, const int* __restrict__ st) {
    __shared__ unsigned short Asm[2][2 * 2 * 128 * 8];   // 2 x 8192 B
    __shared__ unsigned short Bsm[2][12 * 512];          // 2 x 12288 B
    step_body<0>(hp, h, wp, bhh, giTab, st, Asm[0], Asm[1], Bsm[0], Bsm[1]);
}

__global__ __launch_bounds__(256, 3) void k_stepB(
        const unsigned short* __restrict__ hp, float* __restrict__ h,
        const unsigned short* __restrict__ wp, const float* __restrict__ bhh,
        const float* __restrict__ giTab, const int* __restrict__ st) {
    __shared__ unsigned short Asm[2][2 * 2 * 128 * 8];
    __shared__ unsigned short Bsm[2][12 * 512];
    step_body<1>(hp, h, wp, bhh, giTab, st, Asm[0], Asm[1], Bsm[0], Bsm[1]);
}

// ---------------- proj: logits + gumbel argmax + one-hot + EOS + plane write ----------------
__global__ __launch_bounds__(256) void k_projP(const float* __restrict__ hnew,
        unsigned short* __restrict__ hp,
        const float* __restrict__ pw, const float* __restrict__ pb,
        const float* __restrict__ gum, const float* __restrict__ tau,
        float* __restrict__ msg, float* __restrict__ lenf,
        int* __restrict__ st, int t) {
    const int lane = threadIdx.x & 63;
    const int wv = threadIdx.x >> 6;
    const int b = blockIdx.x * 4 + wv;
    const float* hr = hnew + (size_t)b * Hd;
    float s[Vn] = {};
    float vals[16];
    #pragma unroll
    for (int c0 = 0; c0 < 16; c0 += 4) {
        f4 hv = *(const f4*)(hr + lane * 16 + c0);
        #pragma unroll
        for (int q = 0; q < 4; ++q) vals[c0 + q] = hv[q];
        #pragma unroll
        for (int v = 0; v < Vn; ++v) {
            f4 pv = *(const f4*)(pw + (size_t)v * Hd + lane * 16 + c0);
            #pragma unroll
            for (int q = 0; q < 4; ++q) s[v] = fmaf(hv[q], pv[q], s[v]);
        }
    }
    us8v o0[2], o1[2];
    #pragma unroll
    for (int hh = 0; hh < 2; ++hh)
        #pragma unroll
        for (int e = 0; e < 8; ++e) {
            unsigned short q0, q1;
            split2h(vals[hh * 8 + e], q0, q1);
            o0[hh][e] = q0; o1[hh][e] = q1;
        }
    size_t base = (size_t)b * Hd + lane * 16;
    #pragma unroll
    for (int hh = 0; hh < 2; ++hh) {
        *(us8v*)&hp[0 * PLANE + base + hh * 8] = o0[hh];
        *(us8v*)&hp[1 * PLANE + base + hh * 8] = o1[hh];
    }
    #pragma unroll
    for (int v = 0; v < Vn; ++v)
        #pragma unroll
        for (int off = 32; off > 0; off >>= 1)
            s[v] += __shfl_xor(s[v], off, 64);
    if (lane == 0) {
        const float tv = tau[0];
        float zv[Vn];
        #pragma unroll
        for (int v = 0; v < Vn; ++v)
            zv[v] = (s[v] + pb[v] + gum[(size_t)b * Vn + v]) / tv;
        int idx = 0; float m = zv[0];
        #pragma unroll
        for (int v = 1; v < Vn; ++v)
            if (zv[v] > m) { m = zv[v]; idx = v; }
        float* orow = msg + ((size_t)b * Tn + t) * Vn;
        #pragma unroll
        for (int v = 0; v < Vn; ++v) orow[v] = (v == idx) ? 1.0f : 0.0f;
        const int old = st[b];
        const int fn = old >> 4;
        st[b] = idx | (((fn != 0) || (idx == EOSv)) ? 16 : 0);
        if (idx == EOSv && fn == 0) lenf[b] = (float)(t + 1);
    }
}

extern "C" void kernel_launch(void* const* d_in, const int* in_sizes, int n_in,
                              void* d_out, int out_size, void* d_ws, size_t ws_size,
                              hipStream_t stream) {
    const float* x   = (const float*)d_in[0];
    const float* tau = (const float*)d_in[1];
    const float* fcw = (const float*)d_in[2];
    const float* wih = (const float*)d_in[3];
    const float* whh = (const float*)d_in[4];
    const float* bih = (const float*)d_in[5];
    const float* bhh = (const float*)d_in[6];
    const float* pw  = (const float*)d_in[7];
    const float* pb  = (const float*)d_in[8];
    const float* gum = (const float*)d_in[9];

    float* msg  = (float*)d_out;
    float* lenf = msg + (size_t)Bsz * Tn * Vn;

    // workspace: 281,260,032 B (round-11-proven)
    char* ws = (char*)d_ws;
    float*          h     = (float*)ws;                           // 134,217,728
    unsigned short* hp    = (unsigned short*)(ws + 134217728ull); // 134,217,728 (2 f16 planes)
    unsigned short* wpb   = (unsigned short*)(ws + 268435456ull); //  12,582,912
    float*          giTab = (float*)(ws + 281018368ull);          //     110,592
    int*            st    = (int*)  (ws + 281128960ull);          //     131,072

    k_init<<<Bsz / 256, 256, 0, stream>>>(st, lenf);
    k_prep<<<108, 256, 0, stream>>>(wih, bih, giTab);
    k_prepB<<<3072, 256, 0, stream>>>(whh, wpb);
    k_fcP<<<dim3(Bsz / 64, Hd / 64), 256, 0, stream>>>(x, fcw, h, hp);
    for (int t = 0; t < Tn; ++t) {
        if (t & 1)
            k_stepB<<<4096, 256, 0, stream>>>(hp, h, wpb, bhh, giTab, st);
        else
            k_stepA<<<4096, 256, 0, stream>>>(hp, h, wpb, bhh, giTab, st);
        k_projP<<<Bsz / 4, 256, 0, stream>>>(h, hp, pw, pb,
                                             gum + (size_t)t * Bsz * Vn,
                                             tau, msg, lenf, st, t);
    }
}